// Round 2
// baseline (254.371 us; speedup 1.0000x reference)
//
#include <hip/hip_runtime.h>

#define M_DIM   96
#define IN_DIM  16
#define OUT_DIM 16
#define N_BATCH 4
#define PLANE4  (M_DIM * M_DIM / 4)    // 2304 float4 per (j,k) plane
#define PPB     3                      // planes (i values) per block

typedef float f4 __attribute__((ext_vector_type(4)));

// R3 = CALIBRATION ROUND. Kernel body is identical to R2 (221.5 us total).
// We launch it TWICE back-to-back: the second launch writes byte-identical
// values (idempotent -> correctness preserved), so
//     dur_us(R3) - dur_us(R2)  ==  standalone duration of one eq13 dispatch
// inside the real timed graph. This disambiguates:
//   (a) kernel ~34-40 us (write roofline; rest of the 219 us floor is the
//       harness poison fill @137 us + fixed tiny-dispatch overhead), vs
//   (b) kernel ~66-83 us (~3 TB/s, genuine 2x headroom in the store path).
// R0 (6144 blk / 2 barriers / LDS+div in store loop) and R2 (2048 blk /
// 1 barrier / register-resident) differ by <2 us => structure-insensitive;
// only a direct measurement can steer the next edit.
__global__ __launch_bounds__(256) void eq13_kernel(
    const float* __restrict__ x,      // (N, IN_DIM, M)
    const float* __restrict__ coefs,  // (IN_DIM, OUT_DIM, 4)
    const float* __restrict__ bias,   // (OUT_DIM)
    f4* __restrict__ out4)            // (N, OUT_DIM, M, M, M) as float4
{
    __shared__ float s_y0[M_DIM];
    __shared__ float s_y1[M_DIM];
    __shared__ __align__(16) float s_y2[M_DIM];
    __shared__ float s_red[M_DIM];

    const int bid = blockIdx.x;          // 0 .. 2047
    const int ns  = bid >> 5;            // n*16 + s   (0..63)
    const int ig  = (bid & 31) * PPB;    // first i-plane: 0,3,...,93
    const int n   = ns >> 4;
    const int s   = ns & 15;
    const int t   = threadIdx.x;

    const float bs = bias[s];            // uniform, hoisted above the barrier

    if (t < M_DIM) {
        float y0 = 0.f, y1 = 0.f, y2 = 0.f, y3 = 0.f;
        const float* xb = x + (size_t)n * IN_DIM * M_DIM + t;   // coalesced over t
        const float* cb = coefs + s * 4;
        #pragma unroll
        for (int d = 0; d < IN_DIM; ++d) {
            float xv = xb[d * M_DIM];
            f4 c4 = *(const f4*)(cb + d * OUT_DIM * 4);  // c[d][s][0..3]
            y0 = fmaf(xv, c4.x, y0);
            y1 = fmaf(xv, c4.y, y1);
            y2 = fmaf(xv, c4.z, y2);
            y3 = fmaf(xv, c4.w, y3);
        }
        s_y0[t]  = y0;
        s_y1[t]  = y1;
        s_y2[t]  = y2;
        s_red[t] = y3;
    }
    __syncthreads();   // the only barrier

    // All-wave butterfly reduction of s_red[0..95]: every lane ends with S.
    {
        const int lane = t & 63;
        float v = s_red[lane] + ((lane < 32) ? s_red[lane + 64] : 0.f);
        #pragma unroll
        for (int off = 32; off; off >>= 1) v += __shfl_xor(v, off);
        const float S = v + bs;

        // Hoist per-(t,it) y1[j] + y2[4k..4k+3] into registers (plane-invariant).
        const f4* y2v = (const f4*)s_y2;                 // 24 x float4
        f4 g[9];
        #pragma unroll
        for (int it = 0; it < 9; ++it) {
            int   c  = t + it * 256;      // 0 .. 2303
            int   j  = c / 24;            // row (0..95)
            int   kq = c - j * 24;        // float4 idx along k
            float w  = s_y1[j];
            f4    f  = y2v[kq];
            f.x += w; f.y += w; f.z += w; f.w += w;
            g[it] = f;
        }

        // 3 planes x 2304 float4; inner loop is pure add+store, fully coalesced.
        f4* dst = out4 + (size_t)(ns * M_DIM + ig) * PLANE4;
        #pragma unroll
        for (int p = 0; p < PPB; ++p) {
            const float base = s_y0[ig + p] + S;
            #pragma unroll
            for (int it = 0; it < 9; ++it) {
                f4 f = g[it];
                f.x += base; f.y += base; f.z += base; f.w += base;
                dst[p * PLANE4 + t + it * 256] = f;
            }
        }
    }
}

extern "C" void kernel_launch(void* const* d_in, const int* in_sizes, int n_in,
                              void* d_out, int out_size, void* d_ws, size_t ws_size,
                              hipStream_t stream) {
    const float* x     = (const float*)d_in[0];
    const float* coefs = (const float*)d_in[1];
    const float* bias  = (const float*)d_in[2];
    f4* out4 = (f4*)d_out;

    const int grid = N_BATCH * OUT_DIM * (M_DIM / PPB);   // 2048 blocks
    // CALIBRATION: two identical launches. Second is idempotent (same values);
    // the dur_us delta vs R2 measures one kernel dispatch inside the graph.
    eq13_kernel<<<grid, 256, 0, stream>>>(x, coefs, bias, out4);
    eq13_kernel<<<grid, 256, 0, stream>>>(x, coefs, bias, out4);
}

// Round 3
// 219.802 us; speedup vs baseline: 1.1573x; 1.1573x over previous
//
#include <hip/hip_runtime.h>

#define M_DIM   96
#define IN_DIM  16
#define OUT_DIM 16
#define N_BATCH 4
#define PLANE4  (M_DIM * M_DIM / 4)    // 2304 float4 per plane

typedef float f4 __attribute__((ext_vector_type(4)));

// out[n,s,i,j,k] = Y0[n,s,i] + Y1[n,s,j] + Y2[n,s,k] + S[n,s] + bias[s]
//
// ROOFLINE-VERIFIED (R3 calibration, double-launch delta): one dispatch of
// this kernel = 32.9 us for the 226.5 MB output = 6.88 TB/s effective write
// BW, >= the harness fillBuffer's 6.6-6.7 TB/s on the same buffer. The
// remaining ~186 us of dur_us is the harness's 137 us output-poison fill +
// fixed small-dispatch overhead -- not controllable from kernel_launch.
// Structure-insensitivity confirmed: 6144-blk/2-barrier (this) vs
// 2048-blk/1-barrier/register-resident (R2) differ by <2 us; NT stores and
// plane-chunking both regressed in earlier rounds. Do not restructure.
__global__ __launch_bounds__(256) void eq13_kernel(
    const float* __restrict__ x,      // (N, IN_DIM, M)
    const float* __restrict__ coefs,  // (IN_DIM, OUT_DIM, 4)
    const float* __restrict__ bias,   // (OUT_DIM)
    f4* __restrict__ out4)            // (N, OUT_DIM, M, M, M) as float4
{
    __shared__ float s_y0[M_DIM];
    __shared__ float s_y1[M_DIM];
    __shared__ __align__(16) float s_y2[M_DIM];
    __shared__ float s_red[M_DIM];
    __shared__ float s_S;

    const int bid = blockIdx.x;          // 0 .. 6143
    const int ns  = bid / M_DIM;         // n*16 + s
    const int i   = bid - ns * M_DIM;
    const int n   = ns >> 4;
    const int s   = ns & 15;
    const int t   = threadIdx.x;

    if (t < M_DIM) {
        float y0 = 0.f, y1 = 0.f, y2 = 0.f, y3 = 0.f;
        const float* xb = x + (size_t)n * IN_DIM * M_DIM + t;   // coalesced over t
        const float* cb = coefs + s * 4;
        #pragma unroll
        for (int d = 0; d < IN_DIM; ++d) {
            float xv = xb[d * M_DIM];
            f4 c4 = *(const f4*)(cb + d * OUT_DIM * 4);  // c[d][s][0..3]
            y0 = fmaf(xv, c4.x, y0);
            y1 = fmaf(xv, c4.y, y1);
            y2 = fmaf(xv, c4.z, y2);
            y3 = fmaf(xv, c4.w, y3);
        }
        s_y0[t]  = y0;
        s_y1[t]  = y1;
        s_y2[t]  = y2;
        s_red[t] = y3;
    }
    __syncthreads();

    // Parallel reduction of s_red[0..95] on wave 0 (shuffle, no serial loop).
    if (t < 64) {
        float v = s_red[t] + ((t < 32) ? s_red[t + 64] : 0.f);
        #pragma unroll
        for (int off = 32; off; off >>= 1) v += __shfl_down(v, off);
        if (t == 0) s_S = v + bias[s];
    }
    __syncthreads();

    const float  base = s_y0[i] + s_S;
    const f4*    y2v  = (const f4*)s_y2;                 // 24 x float4
    f4* dst = out4 + (size_t)bid * PLANE4;               // this block's plane

    // 2304 float4 = 9 iters x 256 threads; consecutive lanes -> consecutive
    // 16B stores (perfectly coalesced). Plain stores (NT regressed earlier).
    #pragma unroll
    for (int it = 0; it < 9; ++it) {
        int   c  = t + it * 256;          // 0 .. 2303
        int   j  = c / 24;                // row (0..95)
        int   kq = c - j * 24;            // float4 idx along k
        float v  = base + s_y1[j];
        f4    f  = y2v[kq];
        f.x += v; f.y += v; f.z += v; f.w += v;
        dst[c] = f;
    }
}

extern "C" void kernel_launch(void* const* d_in, const int* in_sizes, int n_in,
                              void* d_out, int out_size, void* d_ws, size_t ws_size,
                              hipStream_t stream) {
    const float* x     = (const float*)d_in[0];
    const float* coefs = (const float*)d_in[1];
    const float* bias  = (const float*)d_in[2];
    f4* out4 = (f4*)d_out;

    const int grid = N_BATCH * OUT_DIM * M_DIM;   // 6144 blocks
    eq13_kernel<<<grid, 256, 0, stream>>>(x, coefs, bias, out4);
}